// Round 1
// baseline (203.732 us; speedup 1.0000x reference)
//
#include <hip/hip_runtime.h>

typedef __attribute__((ext_vector_type(8))) short bf16x8;
typedef __attribute__((ext_vector_type(4))) float f32x4;
typedef unsigned short u16;
typedef unsigned int u32;

#define MFMA16(a,b,c) __builtin_amdgcn_mfma_f32_16x16x32_bf16((a),(b),(c),0,0,0)

// f32 -> bf16 round-to-nearest-even
__device__ __forceinline__ u16 f2bf(float f) {
  u32 u = __builtin_bit_cast(u32, f);
  u += 0x7FFFu + ((u >> 16) & 1u);
  return (u16)(u >> 16);
}

// async 16B global -> LDS (dest must be wave-uniform base + lane*16)
__device__ __forceinline__ void gload16(const u16* g, u16* l) {
  __builtin_amdgcn_global_load_lds(
      (const __attribute__((address_space(1))) u32*)(const void*)g,
      (__attribute__((address_space(3))) u32*)(void*)l, 16, 0, 0);
}

// swizzled 16B fragment read from a [R][64] bf16 LDS tile (chunk = 8-elem unit)
__device__ __forceinline__ bf16x8 ldsfrag(const u16* lds, int row, int chunk) {
  return *(const bf16x8*)(lds + row * 64 + ((chunk ^ (row & 7)) << 3));
}

// ---------------- x f32 -> bf16 ----------------
__global__ __launch_bounds__(256) void convert_x(const float* __restrict__ in,
                                                 u16* __restrict__ out, int n4) {
  int i = blockIdx.x * blockDim.x + threadIdx.x;
  int stride = gridDim.x * blockDim.x;
  for (; i < n4; i += stride) {
    float4 v = ((const float4*)in)[i];
    u32 lo = (u32)f2bf(v.x) | ((u32)f2bf(v.y) << 16);
    u32 hi = (u32)f2bf(v.z) | ((u32)f2bf(v.w) << 16);
    uint2 pv; pv.x = lo; pv.y = hi;
    ((uint2*)out)[i] = pv;
  }
}

// ---------------- W [R][C] f32 -> Wt [C][R] bf16 (R = 1024) ----------------
__global__ __launch_bounds__(256) void transpose_w(const float* __restrict__ in,
                                                   u16* __restrict__ out,
                                                   int R, int C) {
  __shared__ float t[32][33];
  int c0 = blockIdx.x * 32, r0 = blockIdx.y * 32;
  int tc = threadIdx.x & 31, tr = threadIdx.x >> 5;  // tr in 0..7
#pragma unroll
  for (int j = 0; j < 4; ++j) {
    int r = tr + j * 8;
    t[r][tc] = in[(size_t)(r0 + r) * C + c0 + tc];
  }
  __syncthreads();
#pragma unroll
  for (int j = 0; j < 4; ++j) {
    int cc = tr + j * 8;
    out[(size_t)(c0 + cc) * R + r0 + tc] = f2bf(t[tc][cc]);
  }
}

// ---------------- GEMM: C[M,n] = A[M,1024] * Bt[n,1024]^T + bias ----------------
// MODE 0: qkv with scatter epilogue -> Q,K [bh][2048][64], V transposed [bh][64][2048]
// MODE 1: f32 output [M][1024]
template <int MODE>
__global__ __launch_bounds__(256) void gemm_k(
    const u16* __restrict__ A, const u16* __restrict__ Bt,
    const float* __restrict__ bias,
    u16* __restrict__ Qo, u16* __restrict__ Ko, u16* __restrict__ Vt,
    float* __restrict__ Of) {
  __shared__ alignas(16) u16 As[128 * 32];
  __shared__ alignas(16) u16 Bs[128 * 32];
  const int tid = threadIdx.x;
  const int wid = tid >> 6, lane = tid & 63;
  const int g = lane >> 4, lr = lane & 15;
  const int m0 = blockIdx.y * 128, n0 = blockIdx.x * 128;
  const int wr = (wid >> 1) * 64, wc = (wid & 1) * 64;

  f32x4 acc[4][4];
#pragma unroll
  for (int i = 0; i < 4; ++i)
#pragma unroll
    for (int j = 0; j < 4; ++j) acc[i][j] = (f32x4){0.f, 0.f, 0.f, 0.f};

  const u16* Ab = A + (size_t)m0 * 1024;
  const u16* Bb = Bt + (size_t)n0 * 1024;

  for (int kt = 0; kt < 1024; kt += 32) {
#pragma unroll
    for (int i = 0; i < 2; ++i) {
      int s = tid + i * 256;           // 16B chunk id, 512 per tile
      int row = s >> 2, c = s & 3;     // 4 chunks per 32-elem row
      gload16(Ab + row * 1024 + kt + c * 8, As + s * 8);
      gload16(Bb + row * 1024 + kt + c * 8, Bs + s * 8);
    }
    __syncthreads();
    bf16x8 af[4], bfr[4];
#pragma unroll
    for (int i = 0; i < 4; ++i)
      af[i] = *(const bf16x8*)(As + (wr + i * 16 + lr) * 32 + g * 8);
#pragma unroll
    for (int j = 0; j < 4; ++j)
      bfr[j] = *(const bf16x8*)(Bs + (wc + j * 16 + lr) * 32 + g * 8);
#pragma unroll
    for (int i = 0; i < 4; ++i)
#pragma unroll
      for (int j = 0; j < 4; ++j)
        acc[i][j] = MFMA16(af[i], bfr[j], acc[i][j]);
    __syncthreads();
  }

  if constexpr (MODE == 1) {
#pragma unroll
    for (int i = 0; i < 4; ++i) {
      int row = m0 + wr + i * 16 + g * 4;
#pragma unroll
      for (int j = 0; j < 4; ++j) {
        int col = n0 + wc + j * 16 + lr;
        float bv = bias[col];
#pragma unroll
        for (int r = 0; r < 4; ++r)
          Of[(size_t)(row + r) * 1024 + col] = acc[i][j][r] + bv;
      }
    }
  } else {
    const int sel = n0 >> 10;  // 0=Q 1=K 2=V (uniform per block)
#pragma unroll
    for (int i = 0; i < 4; ++i) {
      int row = m0 + wr + i * 16 + g * 4;
      int b = row >> 11, s = row & 2047;
#pragma unroll
      for (int j = 0; j < 4; ++j) {
        int col = n0 + wc + j * 16 + lr;
        float bv = bias[col];
        int nn = col & 1023;
        int h = nn >> 6, hd = nn & 63;
        if (sel == 2) {  // V -> transposed [bh][hd][s], 4 consecutive s per lane
          u16 pk[4];
#pragma unroll
          for (int r = 0; r < 4; ++r) pk[r] = f2bf(acc[i][j][r] + bv);
          uint2 pv;
          pv.x = (u32)pk[0] | ((u32)pk[1] << 16);
          pv.y = (u32)pk[2] | ((u32)pk[3] << 16);
          *(uint2*)(Vt + (size_t)((b * 16 + h) * 64 + hd) * 2048 + s) = pv;
        } else {
          u16* dst = (sel == 0) ? Qo : Ko;
#pragma unroll
          for (int r = 0; r < 4; ++r)
            dst[(size_t)((b * 16 + h) * 2048 + s + r) * 64 + hd] =
                f2bf(acc[i][j][r] + bv);
        }
      }
    }
  }
}

// ---------------- flash attention ----------------
// grid (32 q-tiles, 32 bh); block 256 = 4 waves; each wave owns 16 q-rows.
__global__ __launch_bounds__(256) void attn_k(const u16* __restrict__ Q,
                                              const u16* __restrict__ K,
                                              const u16* __restrict__ Vt,
                                              u16* __restrict__ O) {
  __shared__ alignas(16) u16 Qs[64 * 64];
  __shared__ alignas(16) u16 Ks[64 * 64];
  __shared__ alignas(16) u16 Vs[64 * 64];  // [hd][kv]
  __shared__ alignas(16) u16 Ps[64 * 64];
  const int tid = threadIdx.x;
  const int wid = tid >> 6, lane = tid & 63;
  const int g = lane >> 4, lr = lane & 15;
  const int q0 = blockIdx.x * 64;
  const int bh = blockIdx.y;
  const u16* Qh = Q + (size_t)bh * 2048 * 64;
  const u16* Kh = K + (size_t)bh * 2048 * 64;
  const u16* Vh = Vt + (size_t)bh * 64 * 2048;

  // stage Q tile [64][64], chunk-XOR swizzled via pre-swizzled global source
#pragma unroll
  for (int i = 0; i < 2; ++i) {
    int s = tid + i * 256;
    int row = s >> 3, cp = s & 7, c = cp ^ (row & 7);
    gload16(Qh + (q0 + row) * 64 + c * 8, Qs + s * 8);
  }
  __syncthreads();

  const int qrow = wid * 16 + lr;
  bf16x8 aq0 = ldsfrag(Qs, qrow, g);       // hoisted: Q frags constant
  bf16x8 aq1 = ldsfrag(Qs, qrow, 4 + g);

  f32x4 o[4];
#pragma unroll
  for (int j = 0; j < 4; ++j) o[j] = (f32x4){0.f, 0.f, 0.f, 0.f};
  float mrow[4] = {-1e30f, -1e30f, -1e30f, -1e30f};
  float lrow[4] = {0.f, 0.f, 0.f, 0.f};

  for (int kv0 = 0; kv0 < 2048; kv0 += 64) {
#pragma unroll
    for (int i = 0; i < 2; ++i) {
      int s = tid + i * 256;
      int row = s >> 3, cp = s & 7, c = cp ^ (row & 7);
      gload16(Kh + (kv0 + row) * 64 + c * 8, Ks + s * 8);
      gload16(Vh + row * 2048 + kv0 + c * 8, Vs + s * 8);
    }
    __syncthreads();

    // scores: wave's 16 q-rows x 64 kv
    f32x4 sacc[4];
#pragma unroll
    for (int j = 0; j < 4; ++j) sacc[j] = (f32x4){0.f, 0.f, 0.f, 0.f};
#pragma unroll
    for (int j = 0; j < 4; ++j) {
      bf16x8 b0 = ldsfrag(Ks, j * 16 + lr, g);
      bf16x8 b1 = ldsfrag(Ks, j * 16 + lr, 4 + g);
      sacc[j] = MFMA16(aq0, b0, sacc[j]);
      sacc[j] = MFMA16(aq1, b1, sacc[j]);
    }
#pragma unroll
    for (int j = 0; j < 4; ++j) sacc[j] *= 0.125f;  // SCALE = 64^-0.5

    float rmax[4];
#pragma unroll
    for (int r = 0; r < 4; ++r)
      rmax[r] = fmaxf(fmaxf(sacc[0][r], sacc[1][r]), fmaxf(sacc[2][r], sacc[3][r]));
#pragma unroll
    for (int d = 1; d < 16; d <<= 1)
#pragma unroll
      for (int r = 0; r < 4; ++r)
        rmax[r] = fmaxf(rmax[r], __shfl_xor(rmax[r], d));

#pragma unroll
    for (int r = 0; r < 4; ++r) {
      float mn = fmaxf(mrow[r], rmax[r]);
      float alpha = __expf(mrow[r] - mn);
      mrow[r] = mn;
      float rs = 0.f;
      int prow = wid * 16 + g * 4 + r;
#pragma unroll
      for (int j = 0; j < 4; ++j) {
        float p = __expf(sacc[j][r] - mn);
        rs += p;
        int pcol = j * 16 + lr;
        Ps[prow * 64 + (((pcol >> 3) ^ (prow & 7)) << 3) + (pcol & 7)] = f2bf(p);
      }
#pragma unroll
      for (int d = 1; d < 16; d <<= 1) rs += __shfl_xor(rs, d);
      lrow[r] = lrow[r] * alpha + rs;
#pragma unroll
      for (int j = 0; j < 4; ++j) o[j][r] *= alpha;
    }
    __syncthreads();

    // PV: o += P[16x64] * V[64x64]
    {
      bf16x8 pa0 = ldsfrag(Ps, qrow, g);
      bf16x8 pa1 = ldsfrag(Ps, qrow, 4 + g);
#pragma unroll
      for (int j = 0; j < 4; ++j) {
        bf16x8 v0 = ldsfrag(Vs, j * 16 + lr, g);
        bf16x8 v1 = ldsfrag(Vs, j * 16 + lr, 4 + g);
        o[j] = MFMA16(pa0, v0, o[j]);
        o[j] = MFMA16(pa1, v1, o[j]);
      }
    }
    __syncthreads();
  }

  const int b = bh >> 4, h = bh & 15;
  const int row = q0 + wid * 16 + g * 4;
#pragma unroll
  for (int r = 0; r < 4; ++r) {
    float inv = 1.f / lrow[r];
#pragma unroll
    for (int j = 0; j < 4; ++j)
      O[(size_t)(b * 2048 + row + r) * 1024 + h * 64 + j * 16 + lr] =
          f2bf(o[j][r] * inv);
  }
}

extern "C" void kernel_launch(void* const* d_in, const int* in_sizes, int n_in,
                              void* d_out, int out_size, void* d_ws, size_t ws_size,
                              hipStream_t stream) {
  (void)in_sizes; (void)n_in; (void)out_size; (void)ws_size;
  const float* x = (const float*)d_in[0];
  const float* Wqkv = (const float*)d_in[1];
  const float* bqkv = (const float*)d_in[2];
  const float* Wproj = (const float*)d_in[3];
  const float* bproj = (const float*)d_in[4];
  float* out = (float*)d_out;

  char* ws = (char*)d_ws;
  size_t off = 0;
  auto alloc = [&](size_t bytes) {
    void* p = ws + off;
    off += (bytes + 255) & ~(size_t)255;
    return p;
  };
  u16* xb     = (u16*)alloc((size_t)4096 * 1024 * 2);
  u16* Wqkvt  = (u16*)alloc((size_t)3072 * 1024 * 2);
  u16* Wprojt = (u16*)alloc((size_t)1024 * 1024 * 2);
  u16* Qb     = (u16*)alloc((size_t)32 * 2048 * 64 * 2);
  u16* Kb     = (u16*)alloc((size_t)32 * 2048 * 64 * 2);
  u16* Vtb    = (u16*)alloc((size_t)32 * 64 * 2048 * 2);
  u16* AOb    = (u16*)alloc((size_t)4096 * 1024 * 2);

  convert_x<<<2048, 256, 0, stream>>>(x, xb, 4096 * 1024 / 4);
  transpose_w<<<dim3(96, 32), 256, 0, stream>>>(Wqkv, Wqkvt, 1024, 3072);
  transpose_w<<<dim3(32, 32), 256, 0, stream>>>(Wproj, Wprojt, 1024, 1024);
  gemm_k<0><<<dim3(24, 32), 256, 0, stream>>>(xb, Wqkvt, bqkv, Qb, Kb, Vtb, nullptr);
  attn_k<<<dim3(32, 32), 256, 0, stream>>>(Qb, Kb, Vtb, AOb);
  gemm_k<1><<<dim3(8, 32), 256, 0, stream>>>(AOb, Wprojt, bproj, nullptr, nullptr, nullptr, out);
}

// Round 2
// 164.420 us; speedup vs baseline: 1.2391x; 1.2391x over previous
//
#include <hip/hip_runtime.h>

typedef __attribute__((ext_vector_type(8))) short bf16x8;
typedef __attribute__((ext_vector_type(4))) float f32x4;
typedef unsigned short u16;
typedef unsigned int u32;

#define MFMA16(a,b,c) __builtin_amdgcn_mfma_f32_16x16x32_bf16((a),(b),(c),0,0,0)

#if __has_builtin(__builtin_amdgcn_exp2f)
#define EXP2(x) __builtin_amdgcn_exp2f(x)
#else
#define EXP2(x) __expf((x) * 0.6931471805599453f)
#endif

// f32 -> bf16 round-to-nearest-even
__device__ __forceinline__ u16 f2bf(float f) {
  u32 u = __builtin_bit_cast(u32, f);
  u += 0x7FFFu + ((u >> 16) & 1u);
  return (u16)(u >> 16);
}

// async 16B global -> LDS (dest must be wave-uniform base + lane*16)
__device__ __forceinline__ void gload16(const u16* g, u16* l) {
  __builtin_amdgcn_global_load_lds(
      (const __attribute__((address_space(1))) u32*)(const void*)g,
      (__attribute__((address_space(3))) u32*)(void*)l, 16, 0, 0);
}

// swizzled 16B fragment read from a [R][64] bf16 LDS tile (chunk = 8-elem unit)
__device__ __forceinline__ bf16x8 ldsfrag(const u16* lds, int row, int chunk) {
  return *(const bf16x8*)(lds + row * 64 + ((chunk ^ (row & 7)) << 3));
}

// DPP row_ror-based 16-lane reductions (pure VALU, no LDS traffic)
template <int CTRL>
__device__ __forceinline__ float dpp_mv(float v) {
  return __builtin_bit_cast(float, __builtin_amdgcn_update_dpp(
      0, __builtin_bit_cast(int, v), CTRL, 0xF, 0xF, true));
}
__device__ __forceinline__ float redmax16(float v) {
  v = fmaxf(v, dpp_mv<0x121>(v));  // row_ror:1
  v = fmaxf(v, dpp_mv<0x122>(v));  // row_ror:2
  v = fmaxf(v, dpp_mv<0x124>(v));  // row_ror:4
  v = fmaxf(v, dpp_mv<0x128>(v));  // row_ror:8
  return v;
}
__device__ __forceinline__ float redsum16(float v) {
  v += dpp_mv<0x121>(v);
  v += dpp_mv<0x122>(v);
  v += dpp_mv<0x124>(v);
  v += dpp_mv<0x128>(v);
  return v;
}

// ---------------- x f32 -> bf16 ----------------
__global__ __launch_bounds__(256) void convert_x(const float* __restrict__ in,
                                                 u16* __restrict__ out, int n4) {
  int i = blockIdx.x * blockDim.x + threadIdx.x;
  int stride = gridDim.x * blockDim.x;
  for (; i < n4; i += stride) {
    float4 v = ((const float4*)in)[i];
    u32 lo = (u32)f2bf(v.x) | ((u32)f2bf(v.y) << 16);
    u32 hi = (u32)f2bf(v.z) | ((u32)f2bf(v.w) << 16);
    uint2 pv; pv.x = lo; pv.y = hi;
    ((uint2*)out)[i] = pv;
  }
}

// ---------------- W [R][C] f32 -> Wt [C][R] bf16 (R = 1024) ----------------
__global__ __launch_bounds__(256) void transpose_w(const float* __restrict__ in,
                                                   u16* __restrict__ out,
                                                   int R, int C) {
  __shared__ float t[32][33];
  int c0 = blockIdx.x * 32, r0 = blockIdx.y * 32;
  int tc = threadIdx.x & 31, tr = threadIdx.x >> 5;  // tr in 0..7
#pragma unroll
  for (int j = 0; j < 4; ++j) {
    int r = tr + j * 8;
    t[r][tc] = in[(size_t)(r0 + r) * C + c0 + tc];
  }
  __syncthreads();
#pragma unroll
  for (int j = 0; j < 4; ++j) {
    int cc = tr + j * 8;
    out[(size_t)(c0 + cc) * R + r0 + tc] = f2bf(t[tc][cc]);
  }
}

// ---------------- GEMM: C[M,n] = A[M,1024] * Bt[n,1024]^T + bias ----------------
// MODE 0: qkv with scatter epilogue -> Q,K [bh][2048][64], V transposed [bh][64][2048]
// MODE 1: f32 output [M][1024]
template <int MODE>
__global__ __launch_bounds__(256) void gemm_k(
    const u16* __restrict__ A, const u16* __restrict__ Bt,
    const float* __restrict__ bias,
    u16* __restrict__ Qo, u16* __restrict__ Ko, u16* __restrict__ Vt,
    float* __restrict__ Of) {
  __shared__ alignas(16) u16 As[128 * 32];
  __shared__ alignas(16) u16 Bs[128 * 32];
  const int tid = threadIdx.x;
  const int wid = tid >> 6, lane = tid & 63;
  const int g = lane >> 4, lr = lane & 15;
  const int m0 = blockIdx.y * 128, n0 = blockIdx.x * 128;
  const int wr = (wid >> 1) * 64, wc = (wid & 1) * 64;

  f32x4 acc[4][4];
#pragma unroll
  for (int i = 0; i < 4; ++i)
#pragma unroll
    for (int j = 0; j < 4; ++j) acc[i][j] = (f32x4){0.f, 0.f, 0.f, 0.f};

  const u16* Ab = A + (size_t)m0 * 1024;
  const u16* Bb = Bt + (size_t)n0 * 1024;

  for (int kt = 0; kt < 1024; kt += 32) {
#pragma unroll
    for (int i = 0; i < 2; ++i) {
      int s = tid + i * 256;           // 16B chunk id, 512 per tile
      int row = s >> 2, c = s & 3;     // 4 chunks per 32-elem row
      gload16(Ab + row * 1024 + kt + c * 8, As + s * 8);
      gload16(Bb + row * 1024 + kt + c * 8, Bs + s * 8);
    }
    __syncthreads();
    bf16x8 af[4], bfr[4];
#pragma unroll
    for (int i = 0; i < 4; ++i)
      af[i] = *(const bf16x8*)(As + (wr + i * 16 + lr) * 32 + g * 8);
#pragma unroll
    for (int j = 0; j < 4; ++j)
      bfr[j] = *(const bf16x8*)(Bs + (wc + j * 16 + lr) * 32 + g * 8);
#pragma unroll
    for (int i = 0; i < 4; ++i)
#pragma unroll
      for (int j = 0; j < 4; ++j)
        acc[i][j] = MFMA16(af[i], bfr[j], acc[i][j]);
    __syncthreads();
  }

  if constexpr (MODE == 1) {
#pragma unroll
    for (int i = 0; i < 4; ++i) {
      int row = m0 + wr + i * 16 + g * 4;
#pragma unroll
      for (int j = 0; j < 4; ++j) {
        int col = n0 + wc + j * 16 + lr;
        float bv = bias[col];
#pragma unroll
        for (int r = 0; r < 4; ++r)
          Of[(size_t)(row + r) * 1024 + col] = acc[i][j][r] + bv;
      }
    }
  } else {
    const int sel = n0 >> 10;  // 0=Q 1=K 2=V (uniform per block)
#pragma unroll
    for (int i = 0; i < 4; ++i) {
      int row = m0 + wr + i * 16 + g * 4;
      int b = row >> 11, s = row & 2047;
#pragma unroll
      for (int j = 0; j < 4; ++j) {
        int col = n0 + wc + j * 16 + lr;
        float bv = bias[col];
        int nn = col & 1023;
        int h = nn >> 6, hd = nn & 63;
        if (sel == 2) {  // V -> transposed [bh][hd][s], 4 consecutive s per lane
          u16 pk[4];
#pragma unroll
          for (int r = 0; r < 4; ++r) pk[r] = f2bf(acc[i][j][r] + bv);
          uint2 pv;
          pv.x = (u32)pk[0] | ((u32)pk[1] << 16);
          pv.y = (u32)pk[2] | ((u32)pk[3] << 16);
          *(uint2*)(Vt + (size_t)((b * 16 + h) * 64 + hd) * 2048 + s) = pv;
        } else {
          u16* dst = (sel == 0) ? Qo : Ko;
#pragma unroll
          for (int r = 0; r < 4; ++r)
            dst[(size_t)((b * 16 + h) * 2048 + s + r) * 64 + hd] =
                f2bf(acc[i][j][r] + bv);
        }
      }
    }
  }
}

// ---------------- flash attention (double-buffered, 1 barrier/tile) ----------------
// grid (32 q-tiles, 32 bh); block 256 = 4 waves; each wave owns 16 q-rows.
__global__ __launch_bounds__(256) void attn_k(const u16* __restrict__ Q,
                                              const u16* __restrict__ K,
                                              const u16* __restrict__ Vt,
                                              u16* __restrict__ O) {
  __shared__ alignas(16) u16 Ks[2 * 64 * 64];   // [buf][kv][hd], swizzled
  __shared__ alignas(16) u16 Vs[2 * 64 * 64];   // [buf][hd][kv], swizzled
  __shared__ alignas(16) u16 Ps[64 * 64];       // wave-local rows, swizzled
  const int tid = threadIdx.x;
  const int wid = tid >> 6, lane = tid & 63;
  const int g = lane >> 4, lr = lane & 15;
  const int q0 = blockIdx.x * 64;
  const int bh = blockIdx.y;
  const u16* Qh = Q + (size_t)bh * 2048 * 64;
  const u16* Kh = K + (size_t)bh * 2048 * 64;
  const u16* Vh = Vt + (size_t)bh * 64 * 2048;

  const int qrow = wid * 16 + lr;

  // stage K/V tile 0 into buf 0 (async), then load Q frags straight to regs
  {
#pragma unroll
    for (int i = 0; i < 2; ++i) {
      int s = tid + i * 256;
      int row = s >> 3, cp = s & 7, c = cp ^ (row & 7);
      gload16(Kh + row * 64 + c * 8, Ks + s * 8);
      gload16(Vh + row * 2048 + c * 8, Vs + s * 8);
    }
  }
  const u16* qp = Qh + (size_t)(q0 + qrow) * 64;
  bf16x8 aq0 = *(const bf16x8*)(qp + g * 8);
  bf16x8 aq1 = *(const bf16x8*)(qp + 32 + g * 8);
  __syncthreads();  // drains tile-0 staging

  f32x4 o[4];
#pragma unroll
  for (int j = 0; j < 4; ++j) o[j] = (f32x4){0.f, 0.f, 0.f, 0.f};
  float mraw[4] = {-1e30f, -1e30f, -1e30f, -1e30f};  // running max, raw-score units
  float mC[4] = {0.f, 0.f, 0.f, 0.f};                // mraw * C2 (exp2 domain)
  float lsum[4] = {0.f, 0.f, 0.f, 0.f};              // per-lane partial denominators

  const float C2 = 0.125f * 1.44269504088896f;  // SCALE * log2(e)

  for (int t = 0; t < 32; ++t) {
    const u16* Kc = Ks + (t & 1) * 4096;
    const u16* Vc = Vs + (t & 1) * 4096;
    // issue next tile's staging before compute (hidden under MFMA+softmax)
    if (t < 31) {
      int kvn = (t + 1) * 64;
      u16* Kn = Ks + ((t + 1) & 1) * 4096;
      u16* Vn = Vs + ((t + 1) & 1) * 4096;
#pragma unroll
      for (int i = 0; i < 2; ++i) {
        int s = tid + i * 256;
        int row = s >> 3, cp = s & 7, c = cp ^ (row & 7);
        gload16(Kh + (kvn + row) * 64 + c * 8, Kn + s * 8);
        gload16(Vh + row * 2048 + kvn + c * 8, Vn + s * 8);
      }
    }

    // QK^T: wave's 16 q-rows x 64 kv
    f32x4 sacc[4];
#pragma unroll
    for (int j = 0; j < 4; ++j) sacc[j] = (f32x4){0.f, 0.f, 0.f, 0.f};
#pragma unroll
    for (int j = 0; j < 4; ++j) {
      bf16x8 b0 = ldsfrag(Kc, j * 16 + lr, g);
      bf16x8 b1 = ldsfrag(Kc, j * 16 + lr, 4 + g);
      sacc[j] = MFMA16(aq0, b0, sacc[j]);
      sacc[j] = MFMA16(aq1, b1, sacc[j]);
    }

    // row max (raw units; max is monotone under scaling)
    float rmax[4];
#pragma unroll
    for (int r = 0; r < 4; ++r) {
      rmax[r] = fmaxf(fmaxf(sacc[0][r], sacc[1][r]),
                      fmaxf(sacc[2][r], sacc[3][r]));
      rmax[r] = redmax16(rmax[r]);
    }

    // defer-max: only rescale when a row grew by > 8 (scaled) = 64 raw
    bool up = false;
#pragma unroll
    for (int r = 0; r < 4; ++r) up = up || (rmax[r] > mraw[r] + 64.f);
    if (__any(up)) {
#pragma unroll
      for (int r = 0; r < 4; ++r) {
        float mn = fmaxf(mraw[r], rmax[r]);
        float al = EXP2((mraw[r] - mn) * C2);
        mraw[r] = mn;
        mC[r] = mn * C2;
        lsum[r] *= al;
#pragma unroll
        for (int j = 0; j < 4; ++j) o[j][r] *= al;
      }
    }

    // P = exp2(s*C2 - mC), accumulate per-lane partial denom, store bf16 to Ps
#pragma unroll
    for (int r = 0; r < 4; ++r) {
      int prow = wid * 16 + g * 4 + r;
#pragma unroll
      for (int j = 0; j < 4; ++j) {
        float p = EXP2(__builtin_fmaf(sacc[j][r], C2, -mC[r]));
        lsum[r] += p;
        int pcol = j * 16 + lr;
        Ps[prow * 64 + (((pcol >> 3) ^ (prow & 7)) << 3) + (pcol & 7)] = f2bf(p);
      }
    }

    // PV: o += P[16x64] * V[64x64]  (Ps is wave-local; compiler orders via lgkmcnt)
    {
      bf16x8 pa0 = ldsfrag(Ps, qrow, g);
      bf16x8 pa1 = ldsfrag(Ps, qrow, 4 + g);
#pragma unroll
      for (int j = 0; j < 4; ++j) {
        bf16x8 v0 = ldsfrag(Vc, j * 16 + lr, g);
        bf16x8 v1 = ldsfrag(Vc, j * 16 + lr, 4 + g);
        o[j] = MFMA16(pa0, v0, o[j]);
        o[j] = MFMA16(pa1, v1, o[j]);
      }
    }
    __syncthreads();  // single barrier: buffer handoff + drain of next-tile loads
  }

  // finish: reduce per-lane partial denominators across the 16-lane group
  const int b = bh >> 4, h = bh & 15;
  const int row = q0 + wid * 16 + g * 4;
#pragma unroll
  for (int r = 0; r < 4; ++r) {
    float inv = 1.f / redsum16(lsum[r]);
#pragma unroll
    for (int j = 0; j < 4; ++j)
      O[(size_t)(b * 2048 + row + r) * 1024 + h * 64 + j * 16 + lr] =
          f2bf(o[j][r] * inv);
  }
}

extern "C" void kernel_launch(void* const* d_in, const int* in_sizes, int n_in,
                              void* d_out, int out_size, void* d_ws, size_t ws_size,
                              hipStream_t stream) {
  (void)in_sizes; (void)n_in; (void)out_size; (void)ws_size;
  const float* x = (const float*)d_in[0];
  const float* Wqkv = (const float*)d_in[1];
  const float* bqkv = (const float*)d_in[2];
  const float* Wproj = (const float*)d_in[3];
  const float* bproj = (const float*)d_in[4];
  float* out = (float*)d_out;

  char* ws = (char*)d_ws;
  size_t off = 0;
  auto alloc = [&](size_t bytes) {
    void* p = ws + off;
    off += (bytes + 255) & ~(size_t)255;
    return p;
  };
  u16* xb     = (u16*)alloc((size_t)4096 * 1024 * 2);
  u16* Wqkvt  = (u16*)alloc((size_t)3072 * 1024 * 2);
  u16* Wprojt = (u16*)alloc((size_t)1024 * 1024 * 2);
  u16* Qb     = (u16*)alloc((size_t)32 * 2048 * 64 * 2);
  u16* Kb     = (u16*)alloc((size_t)32 * 2048 * 64 * 2);
  u16* Vtb    = (u16*)alloc((size_t)32 * 64 * 2048 * 2);
  u16* AOb    = (u16*)alloc((size_t)4096 * 1024 * 2);

  convert_x<<<2048, 256, 0, stream>>>(x, xb, 4096 * 1024 / 4);
  transpose_w<<<dim3(96, 32), 256, 0, stream>>>(Wqkv, Wqkvt, 1024, 3072);
  transpose_w<<<dim3(32, 32), 256, 0, stream>>>(Wproj, Wprojt, 1024, 1024);
  gemm_k<0><<<dim3(24, 32), 256, 0, stream>>>(xb, Wqkvt, bqkv, Qb, Kb, Vtb, nullptr);
  attn_k<<<dim3(32, 32), 256, 0, stream>>>(Qb, Kb, Vtb, AOb);
  gemm_k<1><<<dim3(8, 32), 256, 0, stream>>>(AOb, Wprojt, bproj, nullptr, nullptr, nullptr, out);
}

// Round 3
// 154.096 us; speedup vs baseline: 1.3221x; 1.0670x over previous
//
#include <hip/hip_runtime.h>

typedef __attribute__((ext_vector_type(8))) short bf16x8;
typedef __attribute__((ext_vector_type(4))) float f32x4;
typedef unsigned short u16;
typedef unsigned int u32;

#define MFMA16(a,b,c) __builtin_amdgcn_mfma_f32_16x16x32_bf16((a),(b),(c),0,0,0)

#if __has_builtin(__builtin_amdgcn_exp2f)
#define EXP2(x) __builtin_amdgcn_exp2f(x)
#else
#define EXP2(x) __expf((x) * 0.6931471805599453f)
#endif

// f32 -> bf16 round-to-nearest-even
__device__ __forceinline__ u16 f2bf(float f) {
  u32 u = __builtin_bit_cast(u32, f);
  u += 0x7FFFu + ((u >> 16) & 1u);
  return (u16)(u >> 16);
}

// packed pair f32x2 -> bf16x2 (RNE) in one instruction
__device__ __forceinline__ u32 cvtpk(float lo, float hi) {
  u32 r;
  asm("v_cvt_pk_bf16_f32 %0, %1, %2" : "=v"(r) : "v"(lo), "v"(hi));
  return r;
}

// async 16B global -> LDS (dest must be wave-uniform base + lane*16)
__device__ __forceinline__ void gload16(const u16* g, u16* l) {
  __builtin_amdgcn_global_load_lds(
      (const __attribute__((address_space(1))) u32*)(const void*)g,
      (__attribute__((address_space(3))) u32*)(void*)l, 16, 0, 0);
}

// swizzled 16B fragment read from a [R][64] bf16 LDS tile (chunk = 8-elem unit)
__device__ __forceinline__ bf16x8 ldsfrag(const u16* lds, int row, int chunk) {
  return *(const bf16x8*)(lds + row * 64 + ((chunk ^ (row & 7)) << 3));
}

// ---------------- x f32 -> bf16 ----------------
__global__ __launch_bounds__(256) void convert_x(const float* __restrict__ in,
                                                 u16* __restrict__ out, int n4) {
  int i = blockIdx.x * blockDim.x + threadIdx.x;
  int stride = gridDim.x * blockDim.x;
  for (; i < n4; i += stride) {
    float4 v = ((const float4*)in)[i];
    u32 lo = (u32)f2bf(v.x) | ((u32)f2bf(v.y) << 16);
    u32 hi = (u32)f2bf(v.z) | ((u32)f2bf(v.w) << 16);
    uint2 pv; pv.x = lo; pv.y = hi;
    ((uint2*)out)[i] = pv;
  }
}

// ---------------- W [R][C] f32 -> Wt [C][R] bf16 (R = 1024) ----------------
__global__ __launch_bounds__(256) void transpose_w(const float* __restrict__ in,
                                                   u16* __restrict__ out,
                                                   int R, int C) {
  __shared__ float t[32][33];
  int c0 = blockIdx.x * 32, r0 = blockIdx.y * 32;
  int tc = threadIdx.x & 31, tr = threadIdx.x >> 5;  // tr in 0..7
#pragma unroll
  for (int j = 0; j < 4; ++j) {
    int r = tr + j * 8;
    t[r][tc] = in[(size_t)(r0 + r) * C + c0 + tc];
  }
  __syncthreads();
#pragma unroll
  for (int j = 0; j < 4; ++j) {
    int cc = tr + j * 8;
    out[(size_t)(c0 + cc) * R + r0 + tc] = f2bf(t[tc][cc]);
  }
}

// ---------------- GEMM: C[M,n] = A[M,1024] * Bt[n,1024]^T + bias ----------------
// MODE 0: qkv with scatter epilogue -> Q,K [bh][2048][64], V transposed [bh][64][2048]
// MODE 1: f32 output [M][1024]
template <int MODE>
__global__ __launch_bounds__(256) void gemm_k(
    const u16* __restrict__ A, const u16* __restrict__ Bt,
    const float* __restrict__ bias,
    u16* __restrict__ Qo, u16* __restrict__ Ko, u16* __restrict__ Vt,
    float* __restrict__ Of) {
  __shared__ alignas(16) u16 As[128 * 32];
  __shared__ alignas(16) u16 Bs[128 * 32];
  const int tid = threadIdx.x;
  const int wid = tid >> 6, lane = tid & 63;
  const int g = lane >> 4, lr = lane & 15;
  const int m0 = blockIdx.y * 128, n0 = blockIdx.x * 128;
  const int wr = (wid >> 1) * 64, wc = (wid & 1) * 64;

  f32x4 acc[4][4];
#pragma unroll
  for (int i = 0; i < 4; ++i)
#pragma unroll
    for (int j = 0; j < 4; ++j) acc[i][j] = (f32x4){0.f, 0.f, 0.f, 0.f};

  const u16* Ab = A + (size_t)m0 * 1024;
  const u16* Bb = Bt + (size_t)n0 * 1024;

  for (int kt = 0; kt < 1024; kt += 32) {
#pragma unroll
    for (int i = 0; i < 2; ++i) {
      int s = tid + i * 256;           // 16B chunk id, 512 per tile
      int row = s >> 2, c = s & 3;     // 4 chunks per 32-elem row
      gload16(Ab + row * 1024 + kt + c * 8, As + s * 8);
      gload16(Bb + row * 1024 + kt + c * 8, Bs + s * 8);
    }
    __syncthreads();
    bf16x8 af[4], bfr[4];
#pragma unroll
    for (int i = 0; i < 4; ++i)
      af[i] = *(const bf16x8*)(As + (wr + i * 16 + lr) * 32 + g * 8);
#pragma unroll
    for (int j = 0; j < 4; ++j)
      bfr[j] = *(const bf16x8*)(Bs + (wc + j * 16 + lr) * 32 + g * 8);
    __builtin_amdgcn_s_setprio(1);
#pragma unroll
    for (int i = 0; i < 4; ++i)
#pragma unroll
      for (int j = 0; j < 4; ++j)
        acc[i][j] = MFMA16(af[i], bfr[j], acc[i][j]);
    __builtin_amdgcn_s_setprio(0);
    __syncthreads();
  }

  if constexpr (MODE == 1) {
#pragma unroll
    for (int i = 0; i < 4; ++i) {
      int row = m0 + wr + i * 16 + g * 4;
#pragma unroll
      for (int j = 0; j < 4; ++j) {
        int col = n0 + wc + j * 16 + lr;
        float bv = bias[col];
#pragma unroll
        for (int r = 0; r < 4; ++r)
          Of[(size_t)(row + r) * 1024 + col] = acc[i][j][r] + bv;
      }
    }
  } else {
    const int sel = n0 >> 10;  // 0=Q 1=K 2=V (uniform per block)
#pragma unroll
    for (int i = 0; i < 4; ++i) {
      int row = m0 + wr + i * 16 + g * 4;
      int b = row >> 11, s = row & 2047;
#pragma unroll
      for (int j = 0; j < 4; ++j) {
        int col = n0 + wc + j * 16 + lr;
        float bv = bias[col];
        int nn = col & 1023;
        int h = nn >> 6, hd = nn & 63;
        if (sel == 2) {  // V -> transposed [bh][hd][s], 4 consecutive s per lane
          u16 pk[4];
#pragma unroll
          for (int r = 0; r < 4; ++r) pk[r] = f2bf(acc[i][j][r] + bv);
          uint2 pv;
          pv.x = (u32)pk[0] | ((u32)pk[1] << 16);
          pv.y = (u32)pk[2] | ((u32)pk[3] << 16);
          *(uint2*)(Vt + (size_t)((b * 16 + h) * 64 + hd) * 2048 + s) = pv;
        } else {
          u16* dst = (sel == 0) ? Qo : Ko;
#pragma unroll
          for (int r = 0; r < 4; ++r)
            dst[(size_t)((b * 16 + h) * 2048 + s + r) * 64 + hd] =
                f2bf(acc[i][j][r] + bv);
        }
      }
    }
  }
}

// ---------------- flash attention (swapped QK^T, packed in-lane softmax) ----------------
// grid (32 q-tiles, 32 bh); block 256 = 4 waves; each wave owns 16 q-rows.
// Swapped QK: sacc[j][r] = P_raw[q = lane&15][kv = 16j + 4g + r] -> softmax is lane-local.
__global__ __launch_bounds__(256) void attn_k(const u16* __restrict__ Q,
                                              const u16* __restrict__ K,
                                              const u16* __restrict__ Vt,
                                              u16* __restrict__ O) {
  __shared__ alignas(16) u16 Ks[2 * 64 * 64];   // [buf][kv][hd], swizzled
  __shared__ alignas(16) u16 Vs[2 * 64 * 64];   // [buf][hd][kv], swizzled
  __shared__ alignas(16) u32 Ps[4 * 16 * 32];   // per-wave [q=16][kvword=32], swizzled
  const int tid = threadIdx.x;
  const int wid = tid >> 6, lane = tid & 63;
  const int g = lane >> 4, lr = lane & 15;
  const int q0 = blockIdx.x * 64;
  const int bh = blockIdx.y;
  const u16* Qh = Q + (size_t)bh * 2048 * 64;
  const u16* Kh = K + (size_t)bh * 2048 * 64;
  const u16* Vh = Vt + (size_t)bh * 64 * 2048;

  // stage K/V tile 0 into buf 0 (async), then load Q frags straight to regs
#pragma unroll
  for (int i = 0; i < 2; ++i) {
    int s = tid + i * 256;
    int row = s >> 3, cp = s & 7, c = cp ^ (row & 7);
    gload16(Kh + row * 64 + c * 8, Ks + s * 8);
    gload16(Vh + row * 2048 + c * 8, Vs + s * 8);
  }
  // Q as B-operand: lane (g,lr) holds Q[q = q0+wid*16+lr][hd = g*8..] per 32-chunk
  const u16* qp = Qh + (size_t)(q0 + wid * 16 + lr) * 64;
  bf16x8 aq0 = *(const bf16x8*)(qp + g * 8);
  bf16x8 aq1 = *(const bf16x8*)(qp + 32 + g * 8);
  __syncthreads();  // drains tile-0 staging

  u32* pws = Ps + wid * 512 + lr * 32;  // this wave, row q=lr
  const int sw = (lr & 7) << 2;          // word-index XOR swizzle (bits 2..4)
  const int bsrc = 20 * g;               // shfl source base for row broadcasts

  f32x4 o[4];
#pragma unroll
  for (int j = 0; j < 4; ++j) o[j] = (f32x4){0.f, 0.f, 0.f, 0.f};
  float mraw = -1e30f;  // running max for q=lr (raw-score units)
  float mC = 0.f;       // mraw * C2 (exp2 domain)
  float lsum = 0.f;     // per-lane partial denominator (this lane's kv subset)

  const float C2 = 0.125f * 1.44269504088896f;  // SCALE * log2(e)

  for (int t = 0; t < 32; ++t) {
    const u16* Kc = Ks + (t & 1) * 4096;
    const u16* Vc = Vs + (t & 1) * 4096;
    // issue next tile's staging before compute (hidden under MFMA+softmax)
    if (t < 31) {
      int kvn = (t + 1) * 64;
      u16* Kn = Ks + ((t + 1) & 1) * 4096;
      u16* Vn = Vs + ((t + 1) & 1) * 4096;
#pragma unroll
      for (int i = 0; i < 2; ++i) {
        int s = tid + i * 256;
        int row = s >> 3, cp = s & 7, c = cp ^ (row & 7);
        gload16(Kh + (kvn + row) * 64 + c * 8, Kn + s * 8);
        gload16(Vh + row * 2048 + kvn + c * 8, Vn + s * 8);
      }
    }

    // QK^T swapped: A = K rows (kv), B = Q cols (q)
    f32x4 sacc[4];
#pragma unroll
    for (int j = 0; j < 4; ++j) sacc[j] = (f32x4){0.f, 0.f, 0.f, 0.f};
    __builtin_amdgcn_s_setprio(1);
#pragma unroll
    for (int j = 0; j < 4; ++j) {
      bf16x8 k0 = ldsfrag(Kc, j * 16 + lr, g);
      bf16x8 k1 = ldsfrag(Kc, j * 16 + lr, 4 + g);
      sacc[j] = MFMA16(k0, aq0, sacc[j]);
      sacc[j] = MFMA16(k1, aq1, sacc[j]);
    }
    __builtin_amdgcn_s_setprio(0);

    // lane-local row max over this lane's 16 kv values (q = lr)
    float rmax;
    {
      float a = fmaxf(fmaxf(sacc[0][0], sacc[0][1]), fmaxf(sacc[0][2], sacc[0][3]));
      float b = fmaxf(fmaxf(sacc[1][0], sacc[1][1]), fmaxf(sacc[1][2], sacc[1][3]));
      float c = fmaxf(fmaxf(sacc[2][0], sacc[2][1]), fmaxf(sacc[2][2], sacc[2][3]));
      float d = fmaxf(fmaxf(sacc[3][0], sacc[3][1]), fmaxf(sacc[3][2], sacc[3][3]));
      rmax = fmaxf(fmaxf(a, b), fmaxf(c, d));
    }
    // complete the row across the 4 g-groups holding q=lr
    rmax = fmaxf(rmax, __shfl_xor(rmax, 16));
    rmax = fmaxf(rmax, __shfl_xor(rmax, 32));

    // defer-max: only rescale when the row grew by > 8 (scaled) = 64 raw
    if (__any(rmax > mraw + 64.f)) {
      float mn = fmaxf(mraw, rmax);
      float al = EXP2((mraw - mn) * C2);
      mraw = mn;
      mC = mn * C2;
      lsum *= al;
#pragma unroll
      for (int r = 0; r < 4; ++r) {
        float ab = __shfl(al, bsrc + r);  // alpha for output row q=4g+r
        o[0][r] *= ab; o[1][r] *= ab; o[2][r] *= ab; o[3][r] *= ab;
      }
    }

    // P = exp2(s*C2 - mC); pack pairs; 4x ds_write_b64 into per-wave P tile
#pragma unroll
    for (int j = 0; j < 4; ++j) {
      float p0 = EXP2(__builtin_fmaf(sacc[j][0], C2, -mC));
      float p1 = EXP2(__builtin_fmaf(sacc[j][1], C2, -mC));
      float p2 = EXP2(__builtin_fmaf(sacc[j][2], C2, -mC));
      float p3 = EXP2(__builtin_fmaf(sacc[j][3], C2, -mC));
      lsum += (p0 + p1) + (p2 + p3);
      uint2 pv;
      pv.x = cvtpk(p0, p1);
      pv.y = cvtpk(p2, p3);
      *(uint2*)(pws + ((8 * j + 2 * g) ^ sw)) = pv;  // kv words 8j+2g, +1
    }

    // PV: o += P[16x64] * V[64x64]; P A-frags straight from wave-local LDS
    {
      bf16x8 pa0 = *(const bf16x8*)(pws + ((4 * g) ^ sw));        // kv 0..31
      bf16x8 pa1 = *(const bf16x8*)(pws + ((16 + 4 * g) ^ sw));   // kv 32..63
      __builtin_amdgcn_s_setprio(1);
#pragma unroll
      for (int j = 0; j < 4; ++j) {
        bf16x8 v0 = ldsfrag(Vc, j * 16 + lr, g);
        bf16x8 v1 = ldsfrag(Vc, j * 16 + lr, 4 + g);
        o[j] = MFMA16(pa0, v0, o[j]);
        o[j] = MFMA16(pa1, v1, o[j]);
      }
      __builtin_amdgcn_s_setprio(0);
    }
    __syncthreads();  // single barrier: buffer handoff + drain of next-tile loads
  }

  // finish: complete the denominator for q=lr, then broadcast to output rows
  float ls = lsum + __shfl_xor(lsum, 16);
  ls += __shfl_xor(ls, 32);
  float inv = 1.f / ls;
  const int b = bh >> 4, h = bh & 15;
  const int row = q0 + wid * 16 + g * 4;
#pragma unroll
  for (int r = 0; r < 4; ++r) {
    float ib = __shfl(inv, bsrc + r);
#pragma unroll
    for (int j = 0; j < 4; ++j)
      O[(size_t)(b * 2048 + row + r) * 1024 + h * 64 + j * 16 + lr] =
          f2bf(o[j][r] * ib);
  }
}

extern "C" void kernel_launch(void* const* d_in, const int* in_sizes, int n_in,
                              void* d_out, int out_size, void* d_ws, size_t ws_size,
                              hipStream_t stream) {
  (void)in_sizes; (void)n_in; (void)out_size; (void)ws_size;
  const float* x = (const float*)d_in[0];
  const float* Wqkv = (const float*)d_in[1];
  const float* bqkv = (const float*)d_in[2];
  const float* Wproj = (const float*)d_in[3];
  const float* bproj = (const float*)d_in[4];
  float* out = (float*)d_out;

  char* ws = (char*)d_ws;
  size_t off = 0;
  auto alloc = [&](size_t bytes) {
    void* p = ws + off;
    off += (bytes + 255) & ~(size_t)255;
    return p;
  };
  u16* xb     = (u16*)alloc((size_t)4096 * 1024 * 2);
  u16* Wqkvt  = (u16*)alloc((size_t)3072 * 1024 * 2);
  u16* Wprojt = (u16*)alloc((size_t)1024 * 1024 * 2);
  u16* Qb     = (u16*)alloc((size_t)32 * 2048 * 64 * 2);
  u16* Kb     = (u16*)alloc((size_t)32 * 2048 * 64 * 2);
  u16* Vtb    = (u16*)alloc((size_t)32 * 64 * 2048 * 2);
  u16* AOb    = (u16*)alloc((size_t)4096 * 1024 * 2);

  convert_x<<<2048, 256, 0, stream>>>(x, xb, 4096 * 1024 / 4);
  transpose_w<<<dim3(96, 32), 256, 0, stream>>>(Wqkv, Wqkvt, 1024, 3072);
  transpose_w<<<dim3(32, 32), 256, 0, stream>>>(Wproj, Wprojt, 1024, 1024);
  gemm_k<0><<<dim3(24, 32), 256, 0, stream>>>(xb, Wqkvt, bqkv, Qb, Kb, Vtb, nullptr);
  attn_k<<<dim3(32, 32), 256, 0, stream>>>(Qb, Kb, Vtb, AOb);
  gemm_k<1><<<dim3(8, 32), 256, 0, stream>>>(AOb, Wprojt, bproj, nullptr, nullptr, nullptr, out);
}

// Round 6
// 151.033 us; speedup vs baseline: 1.3489x; 1.0203x over previous
//
#include <hip/hip_runtime.h>

typedef __attribute__((ext_vector_type(8))) short bf16x8;
typedef __attribute__((ext_vector_type(4))) float f32x4;
typedef __attribute__((ext_vector_type(16))) float f32x16;
typedef unsigned short u16;
typedef unsigned int u32;

#define MFMA16(a,b,c) __builtin_amdgcn_mfma_f32_16x16x32_bf16((a),(b),(c),0,0,0)
#define MFMA32(a,b,c) __builtin_amdgcn_mfma_f32_32x32x16_bf16((a),(b),(c),0,0,0)

#if __has_builtin(__builtin_amdgcn_exp2f)
#define EXP2(x) __builtin_amdgcn_exp2f(x)
#else
#define EXP2(x) __expf((x) * 0.6931471805599453f)
#endif

// f32 -> bf16 round-to-nearest-even
__device__ __forceinline__ u16 f2bf(float f) {
  u32 u = __builtin_bit_cast(u32, f);
  u += 0x7FFFu + ((u >> 16) & 1u);
  return (u16)(u >> 16);
}

// packed pair f32x2 -> bf16x2 (RNE) in one instruction
__device__ __forceinline__ u32 cvtpk(float lo, float hi) {
  u32 r;
  asm("v_cvt_pk_bf16_f32 %0, %1, %2" : "=v"(r) : "v"(lo), "v"(hi));
  return r;
}

// async 16B global -> LDS (dest must be wave-uniform base + lane*16)
__device__ __forceinline__ void gload16(const u16* g, u16* l) {
  __builtin_amdgcn_global_load_lds(
      (const __attribute__((address_space(1))) u32*)(const void*)g,
      (__attribute__((address_space(3))) u32*)(void*)l, 16, 0, 0);
}

// swizzled 16B fragment read from a [R][64] bf16 LDS tile (chunk = 8-elem unit)
__device__ __forceinline__ bf16x8 ldsfrag(const u16* lds, int row, int chunk) {
  return *(const bf16x8*)(lds + row * 64 + ((chunk ^ (row & 7)) << 3));
}

// ---------------- x f32 -> bf16 ----------------
__global__ __launch_bounds__(256) void convert_x(const float* __restrict__ in,
                                                 u16* __restrict__ out, int n4) {
  int i = blockIdx.x * blockDim.x + threadIdx.x;
  int stride = gridDim.x * blockDim.x;
  for (; i < n4; i += stride) {
    float4 v = ((const float4*)in)[i];
    u32 lo = (u32)f2bf(v.x) | ((u32)f2bf(v.y) << 16);
    u32 hi = (u32)f2bf(v.z) | ((u32)f2bf(v.w) << 16);
    uint2 pv; pv.x = lo; pv.y = hi;
    ((uint2*)out)[i] = pv;
  }
}

// ---------------- W [R][C] f32 -> Wt [C][R] bf16 (R = 1024) ----------------
__global__ __launch_bounds__(256) void transpose_w(const float* __restrict__ in,
                                                   u16* __restrict__ out,
                                                   int R, int C) {
  __shared__ float t[32][33];
  int c0 = blockIdx.x * 32, r0 = blockIdx.y * 32;
  int tc = threadIdx.x & 31, tr = threadIdx.x >> 5;  // tr in 0..7
#pragma unroll
  for (int j = 0; j < 4; ++j) {
    int r = tr + j * 8;
    t[r][tc] = in[(size_t)(r0 + r) * C + c0 + tc];
  }
  __syncthreads();
#pragma unroll
  for (int j = 0; j < 4; ++j) {
    int cc = tr + j * 8;
    out[(size_t)(c0 + cc) * R + r0 + tc] = f2bf(t[tc][cc]);
  }
}

// ---------------- GEMM: C[M,n] = A[M,1024] * Bt[n,1024]^T + bias ----------------
// MODE 0: qkv with scatter epilogue -> Q,K [bh][2048][64], V transposed [bh][64][2048]
// MODE 1: f32 output [M][1024]
template <int MODE>
__global__ __launch_bounds__(256) void gemm_k(
    const u16* __restrict__ A, const u16* __restrict__ Bt,
    const float* __restrict__ bias,
    u16* __restrict__ Qo, u16* __restrict__ Ko, u16* __restrict__ Vt,
    float* __restrict__ Of) {
  __shared__ alignas(16) u16 As[128 * 32];
  __shared__ alignas(16) u16 Bs[128 * 32];
  const int tid = threadIdx.x;
  const int wid = tid >> 6, lane = tid & 63;
  const int g = lane >> 4, lr = lane & 15;
  const int m0 = blockIdx.y * 128, n0 = blockIdx.x * 128;
  const int wr = (wid >> 1) * 64, wc = (wid & 1) * 64;

  f32x4 acc[4][4];
#pragma unroll
  for (int i = 0; i < 4; ++i)
#pragma unroll
    for (int j = 0; j < 4; ++j) acc[i][j] = (f32x4){0.f, 0.f, 0.f, 0.f};

  const u16* Ab = A + (size_t)m0 * 1024;
  const u16* Bb = Bt + (size_t)n0 * 1024;

  for (int kt = 0; kt < 1024; kt += 32) {
#pragma unroll
    for (int i = 0; i < 2; ++i) {
      int s = tid + i * 256;           // 16B chunk id, 512 per tile
      int row = s >> 2, c = s & 3;     // 4 chunks per 32-elem row
      gload16(Ab + row * 1024 + kt + c * 8, As + s * 8);
      gload16(Bb + row * 1024 + kt + c * 8, Bs + s * 8);
    }
    __syncthreads();
    bf16x8 af[4], bfr[4];
#pragma unroll
    for (int i = 0; i < 4; ++i)
      af[i] = *(const bf16x8*)(As + (wr + i * 16 + lr) * 32 + g * 8);
#pragma unroll
    for (int j = 0; j < 4; ++j)
      bfr[j] = *(const bf16x8*)(Bs + (wc + j * 16 + lr) * 32 + g * 8);
    __builtin_amdgcn_s_setprio(1);
#pragma unroll
    for (int i = 0; i < 4; ++i)
#pragma unroll
      for (int j = 0; j < 4; ++j)
        acc[i][j] = MFMA16(af[i], bfr[j], acc[i][j]);
    __builtin_amdgcn_s_setprio(0);
    __syncthreads();
  }

  if constexpr (MODE == 1) {
#pragma unroll
    for (int i = 0; i < 4; ++i) {
      int row = m0 + wr + i * 16 + g * 4;
#pragma unroll
      for (int j = 0; j < 4; ++j) {
        int col = n0 + wc + j * 16 + lr;
        float bv = bias[col];
#pragma unroll
        for (int r = 0; r < 4; ++r)
          Of[(size_t)(row + r) * 1024 + col] = acc[i][j][r] + bv;
      }
    }
  } else {
    const int sel = n0 >> 10;  // 0=Q 1=K 2=V (uniform per block)
#pragma unroll
    for (int i = 0; i < 4; ++i) {
      int row = m0 + wr + i * 16 + g * 4;
      int b = row >> 11, s = row & 2047;
#pragma unroll
      for (int j = 0; j < 4; ++j) {
        int col = n0 + wc + j * 16 + lr;
        float bv = bias[col];
        int nn = col & 1023;
        int h = nn >> 6, hd = nn & 63;
        if (sel == 2) {  // V -> transposed [bh][hd][s], 4 consecutive s per lane
          u16 pk[4];
#pragma unroll
          for (int r = 0; r < 4; ++r) pk[r] = f2bf(acc[i][j][r] + bv);
          uint2 pv;
          pv.x = (u32)pk[0] | ((u32)pk[1] << 16);
          pv.y = (u32)pk[2] | ((u32)pk[3] << 16);
          *(uint2*)(Vt + (size_t)((b * 16 + h) * 64 + hd) * 2048 + s) = pv;
        } else {
          u16* dst = (sel == 0) ? Qo : Ko;
#pragma unroll
          for (int r = 0; r < 4; ++r)
            dst[(size_t)((b * 16 + h) * 2048 + s + r) * 64 + hd] =
                f2bf(acc[i][j][r] + bv);
        }
      }
    }
  }
}

// ---------------- flash attention: 32x32 MFMA, QBLK=32/wave, PV via LDS ----
// grid (16 q-tiles of 128, 32 bh); block 256 = 4 waves; wave owns 32 q-rows.
// Swapped QK^T (A=K,B=Q), both operands read with the SAME claimed k-layout
// (contiguous-8) -> any true-layout permutation cancels. C/D layout (verified
// m74/m101): col=lane&31 (=q), row=(reg&3)+8*(reg>>2)+4*(lane>>5) (=kv).
// PV: P is written to a per-wave LDS tile at TRUE kv coords, then A-frag and
// V B-frag are both read with the same contiguous-8 claim -> cancels again.
__global__ __launch_bounds__(256, 2) void attn_k(const u16* __restrict__ Q,
                                                 const u16* __restrict__ K,
                                                 const u16* __restrict__ Vt,
                                                 u16* __restrict__ O) {
  __shared__ alignas(16) u16 Ks[2 * 64 * 64];   // [buf][kv][hd], chunk-XOR swizzled
  __shared__ alignas(16) u16 Vs[2 * 64 * 64];   // [buf][hd][kv], chunk-XOR swizzled
  __shared__ alignas(16) u32 Ps[4 * 32 * 32];   // per-wave [q=32][kv-word=32], swizzled
  const int tid = threadIdx.x;
  const int wid = tid >> 6, lane = tid & 63;
  const int l31 = lane & 31, b5 = lane >> 5;
  const int bh = blockIdx.y;
  const u16* Qh = Q + (size_t)bh * 2048 * 64;
  const u16* Kh = K + (size_t)bh * 2048 * 64;
  const u16* Vh = Vt + (size_t)bh * 64 * 2048;

  // stage K/V tile 0 into buf 0 (async)
#pragma unroll
  for (int i = 0; i < 2; ++i) {
    int s = tid + i * 256;
    int row = s >> 3, c = (s & 7) ^ (row & 7);
    gload16(Kh + row * 64 + c * 8, Ks + s * 8);
    gload16(Vh + row * 2048 + c * 8, Vs + s * 8);
  }

  // Q B-frags (registers, constant over kv tiles): col q = qbase+l31,
  // claimed k-layout contiguous-8 (matches K A-frag reads -> cancels).
  const int qbase = blockIdx.x * 128 + wid * 32;
  const u16* qp = Qh + (size_t)(qbase + l31) * 64 + b5 * 8;
  bf16x8 qf[4];
#pragma unroll
  for (int c = 0; c < 4; ++c) qf[c] = *(const bf16x8*)(qp + 16 * c);
  __syncthreads();  // drains tile-0 staging

  // per-wave P tile base (u32 words), row q = l31; XOR swizzle on word bits 2..4
  u32* pw = Ps + wid * 1024 + l31 * 32;
  const int swz = (l31 & 7) << 2;

  f32x16 accO0, accO1;
#pragma unroll
  for (int r = 0; r < 16; ++r) { accO0[r] = 0.f; accO1[r] = 0.f; }
  float mraw = -1e30f;  // running max for q=l31 (raw-score units)
  float mC = 0.f;       // mraw * C2 (exp2 domain)
  float lsum = 0.f;     // per-lane partial denominator

  const float C2 = 0.125f * 1.44269504088896f;  // SCALE * log2(e)

  for (int t = 0; t < 32; ++t) {
    const u16* Kc = Ks + (t & 1) * 4096;
    const u16* Vc = Vs + (t & 1) * 4096;
    // issue next tile's staging before compute (hidden under MFMA+softmax)
    if (t < 31) {
      int kvn = (t + 1) * 64;
      u16* Kn = Ks + ((t + 1) & 1) * 4096;
      u16* Vn = Vs + ((t + 1) & 1) * 4096;
#pragma unroll
      for (int i = 0; i < 2; ++i) {
        int s = tid + i * 256;
        int row = s >> 3, c = (s & 7) ^ (row & 7);
        gload16(Kh + (kvn + row) * 64 + c * 8, Kn + s * 8);
        gload16(Vh + row * 2048 + kvn + c * 8, Vn + s * 8);
      }
    }

    // QK^T swapped (A=K, B=Q): same claimed layout on both operands.
    f32x16 s0, s1;
#pragma unroll
    for (int r = 0; r < 16; ++r) { s0[r] = 0.f; s1[r] = 0.f; }
    __builtin_amdgcn_s_setprio(1);
#pragma unroll
    for (int c = 0; c < 4; ++c) {
      bf16x8 k0 = ldsfrag(Kc, l31, 2 * c + b5);
      bf16x8 k1 = ldsfrag(Kc, 32 + l31, 2 * c + b5);
      s0 = MFMA32(k0, qf[c], s0);
      s1 = MFMA32(k1, qf[c], s1);
    }
    __builtin_amdgcn_s_setprio(0);

    // lane-local max over this lane's 32 kv values (q = l31)
    float rmax;
    {
      float a0 = fmaxf(fmaxf(s0[0], s0[1]), fmaxf(s0[2], s0[3]));
      float a1 = fmaxf(fmaxf(s0[4], s0[5]), fmaxf(s0[6], s0[7]));
      float a2 = fmaxf(fmaxf(s0[8], s0[9]), fmaxf(s0[10], s0[11]));
      float a3 = fmaxf(fmaxf(s0[12], s0[13]), fmaxf(s0[14], s0[15]));
      float b0 = fmaxf(fmaxf(s1[0], s1[1]), fmaxf(s1[2], s1[3]));
      float b1 = fmaxf(fmaxf(s1[4], s1[5]), fmaxf(s1[6], s1[7]));
      float b2 = fmaxf(fmaxf(s1[8], s1[9]), fmaxf(s1[10], s1[11]));
      float b3 = fmaxf(fmaxf(s1[12], s1[13]), fmaxf(s1[14], s1[15]));
      rmax = fmaxf(fmaxf(fmaxf(a0, a1), fmaxf(a2, a3)),
                   fmaxf(fmaxf(b0, b1), fmaxf(b2, b3)));
    }
    rmax = fmaxf(rmax, __shfl_xor(rmax, 32));  // combine the two kv-subsets of row q

    // defer-max: only rescale when a row grew by > 8 (scaled) = 64 raw
    if (__any(rmax > mraw + 64.f)) {
      float mn = fmaxf(mraw, rmax);
      float al = EXP2((mraw - mn) * C2);
      mraw = mn;
      mC = mn * C2;
      lsum *= al;
#pragma unroll
      for (int r = 0; r < 16; ++r) {
        float ar = __shfl(al, (r & 3) + 8 * (r >> 2) + 4 * b5);
        accO0[r] *= ar;
        accO1[r] *= ar;
      }
    }

    // P = exp2(s*C2 - mC); pack reg-adjacent (=kv-adjacent) pairs; write to
    // per-wave P tile at TRUE kv coords: regs (2i,2i+1) -> kv base
    // ((2i)&3)+8*((2i)>>2)+4*b5 -> word ((i&1)+4*(i>>1)+2*b5), s1 half +16.
    u32 w0[8], w1[8];
#pragma unroll
    for (int i = 0; i < 8; ++i) {
      float p0 = EXP2(__builtin_fmaf(s0[2 * i], C2, -mC));
      float p1 = EXP2(__builtin_fmaf(s0[2 * i + 1], C2, -mC));
      float p2 = EXP2(__builtin_fmaf(s1[2 * i], C2, -mC));
      float p3 = EXP2(__builtin_fmaf(s1[2 * i + 1], C2, -mC));
      lsum += (p0 + p1) + (p2 + p3);
      w0[i] = cvtpk(p0, p1);
      w1[i] = cvtpk(p2, p3);
    }
#pragma unroll
    for (int j = 0; j < 4; ++j) {
      uint2 a; a.x = w0[2 * j]; a.y = w0[2 * j + 1];
      uint2 b; b.x = w1[2 * j]; b.y = w1[2 * j + 1];
      *(uint2*)(pw + ((4 * j + 2 * b5) ^ swz)) = a;        // kv words 4j+2b5,+1
      *(uint2*)(pw + ((16 + 4 * j + 2 * b5) ^ swz)) = b;   // s1 half
    }

    // PV: A-frag (P) and B-frag (V) both read with claimed contiguous-8 ->
    // true-layout permutation cancels. Chunk c covers kv 16c..16c+15.
    __builtin_amdgcn_s_setprio(1);
#pragma unroll
    for (int c = 0; c < 4; ++c) {
      bf16x8 pf = *(const bf16x8*)(pw + ((8 * c + 4 * b5) ^ swz));
      bf16x8 v0 = ldsfrag(Vc, l31, 2 * c + b5);
      bf16x8 v1 = ldsfrag(Vc, 32 + l31, 2 * c + b5);
      accO0 = MFMA32(pf, v0, accO0);
      accO1 = MFMA32(pf, v1, accO1);
    }
    __builtin_amdgcn_s_setprio(0);
    __syncthreads();  // single barrier: buffer handoff + drain of next-tile loads
  }

  // finish: combine half-lane partial denominators, broadcast 1/l per output row
  float ls = lsum + __shfl_xor(lsum, 32);
  float inv = 1.f / ls;
  const int b = bh >> 4, h = bh & 15;
#pragma unroll
  for (int r = 0; r < 16; ++r) {
    float ir = __shfl(inv, (r & 3) + 8 * (r >> 2) + 4 * b5);
    int qr = qbase + (r & 3) + 8 * (r >> 2) + 4 * b5;
    size_t rowoff = (size_t)(b * 2048 + qr) * 1024 + h * 64;
    O[rowoff + l31] = f2bf(accO0[r] * ir);
    O[rowoff + 32 + l31] = f2bf(accO1[r] * ir);
  }
}

extern "C" void kernel_launch(void* const* d_in, const int* in_sizes, int n_in,
                              void* d_out, int out_size, void* d_ws, size_t ws_size,
                              hipStream_t stream) {
  (void)in_sizes; (void)n_in; (void)out_size; (void)ws_size;
  const float* x = (const float*)d_in[0];
  const float* Wqkv = (const float*)d_in[1];
  const float* bqkv = (const float*)d_in[2];
  const float* Wproj = (const float*)d_in[3];
  const float* bproj = (const float*)d_in[4];
  float* out = (float*)d_out;

  char* ws = (char*)d_ws;
  size_t off = 0;
  auto alloc = [&](size_t bytes) {
    void* p = ws + off;
    off += (bytes + 255) & ~(size_t)255;
    return p;
  };
  u16* xb     = (u16*)alloc((size_t)4096 * 1024 * 2);
  u16* Wqkvt  = (u16*)alloc((size_t)3072 * 1024 * 2);
  u16* Wprojt = (u16*)alloc((size_t)1024 * 1024 * 2);
  u16* Qb     = (u16*)alloc((size_t)32 * 2048 * 64 * 2);
  u16* Kb     = (u16*)alloc((size_t)32 * 2048 * 64 * 2);
  u16* Vtb    = (u16*)alloc((size_t)32 * 64 * 2048 * 2);
  u16* AOb    = (u16*)alloc((size_t)4096 * 1024 * 2);

  convert_x<<<2048, 256, 0, stream>>>(x, xb, 4096 * 1024 / 4);
  transpose_w<<<dim3(96, 32), 256, 0, stream>>>(Wqkv, Wqkvt, 1024, 3072);
  transpose_w<<<dim3(32, 32), 256, 0, stream>>>(Wproj, Wprojt, 1024, 1024);
  gemm_k<0><<<dim3(24, 32), 256, 0, stream>>>(xb, Wqkvt, bqkv, Qb, Kb, Vtb, nullptr);
  attn_k<<<dim3(16, 32), 256, 0, stream>>>(Qb, Kb, Vtb, AOb);
  gemm_k<1><<<dim3(8, 32), 256, 0, stream>>>(AOb, Wprojt, bproj, nullptr, nullptr, nullptr, out);
}